// Round 1
// baseline (1294.715 us; speedup 1.0000x reference)
//
#include <hip/hip_runtime.h>
#include <math.h>

// ---------------------------------------------------------------------------
// GINE 2-layer GNN, N=100K nodes (D 32->64->64), E=3.2M edges, ED=16.
// Edge pass: group-per-edge, We columns in registers, shfl-broadcast of ea,
//            fp32 atomicAdd aggregation.
// Node pass: wave-per-node GEMV, weights in registers, shfl broadcast.
// ---------------------------------------------------------------------------

__global__ __launch_bounds__(256) void k_edge1(
    const float* __restrict__ x, const float* __restrict__ ea,
    const int* __restrict__ src, const int* __restrict__ dst,
    const float* __restrict__ We, const float* __restrict__ be,
    float* __restrict__ aggr, int E)
{
  const int lane = threadIdx.x & 31;
  float wcol[16];
#pragma unroll
  for (int k = 0; k < 16; ++k) wcol[k] = We[k * 32 + lane];
  const float bias = be[lane];
  const int gid  = (blockIdx.x * blockDim.x + threadIdx.x) >> 5;
  const int ngrp = (gridDim.x * blockDim.x) >> 5;
  for (int e = gid; e < E; e += ngrp) {
    const int s = src[e], d = dst[e];
    const float eav = (lane < 16) ? ea[e * 16 + lane] : 0.f;
    float acc = bias;
#pragma unroll
    for (int k = 0; k < 16; ++k)
      acc = fmaf(__shfl(eav, k, 32), wcol[k], acc);
    const float xv = x[s * 32 + lane];
    const float m = fmaxf(xv + acc, 0.f);
    atomicAdd(&aggr[d * 32 + lane], m);
  }
}

__global__ __launch_bounds__(256) void k_edge2(
    const float* __restrict__ h1, const float* __restrict__ ea,
    const int* __restrict__ src, const int* __restrict__ dst,
    const float* __restrict__ We, const float* __restrict__ be,
    float* __restrict__ aggr, int E)
{
  const int lane = threadIdx.x & 63;
  float wcol[16];
#pragma unroll
  for (int k = 0; k < 16; ++k) wcol[k] = We[k * 64 + lane];
  const float bias = be[lane];
  const int gid  = (blockIdx.x * blockDim.x + threadIdx.x) >> 6;
  const int ngrp = (gridDim.x * blockDim.x) >> 6;
  for (int e = gid; e < E; e += ngrp) {
    const int s = src[e], d = dst[e];
    const float eav = (lane < 16) ? ea[e * 16 + lane] : 0.f;
    float acc = bias;
#pragma unroll
    for (int k = 0; k < 16; ++k)
      acc = fmaf(__shfl(eav, k, 64), wcol[k], acc);
    const float hv = h1[s * 64 + lane];
    const float m = fmaxf(hv + acc, 0.f);
    atomicAdd(&aggr[d * 64 + lane], m);
  }
}

__global__ __launch_bounds__(256) void k_node1(
    const float* __restrict__ x, const float* __restrict__ aggr,
    const float* __restrict__ Wa, const float* __restrict__ ba,
    const float* __restrict__ Wb, const float* __restrict__ bb,
    float* __restrict__ h1, int N)
{
  const int lane = threadIdx.x & 63;
  float wa[32], wb[64];
#pragma unroll
  for (int k = 0; k < 32; ++k) wa[k] = Wa[k * 64 + lane];
#pragma unroll
  for (int k = 0; k < 64; ++k) wb[k] = Wb[k * 64 + lane];
  const float ba_l = ba[lane], bb_l = bb[lane];
  const int wid = (blockIdx.x * blockDim.x + threadIdx.x) >> 6;
  const int nw  = (gridDim.x * blockDim.x) >> 6;
  for (int n = wid; n < N; n += nw) {
    const float hp = (lane < 32) ? (x[n * 32 + lane] + aggr[n * 32 + lane]) : 0.f;
    float t = ba_l;
#pragma unroll
    for (int k = 0; k < 32; ++k)
      t = fmaf(__shfl(hp, k, 64), wa[k], t);
    t = fmaxf(t, 0.f);
    float h = bb_l;
#pragma unroll
    for (int k = 0; k < 64; ++k)
      h = fmaf(__shfl(t, k, 64), wb[k], h);
    h1[n * 64 + lane] = h;
  }
}

__global__ __launch_bounds__(256) void k_node2(
    const float* __restrict__ h1, const float* __restrict__ aggr,
    const float* __restrict__ Wa, const float* __restrict__ ba,
    const float* __restrict__ Wb, const float* __restrict__ bb,
    float* __restrict__ gsum, int N)
{
  const int lane = threadIdx.x & 63;
  const int wv = threadIdx.x >> 6;
  float wa[64], wb[64];
#pragma unroll
  for (int k = 0; k < 64; ++k) wa[k] = Wa[k * 64 + lane];
#pragma unroll
  for (int k = 0; k < 64; ++k) wb[k] = Wb[k * 64 + lane];
  const float ba_l = ba[lane], bb_l = bb[lane];
  float psum = 0.f;
  const int wid = (blockIdx.x * blockDim.x + threadIdx.x) >> 6;
  const int nw  = (gridDim.x * blockDim.x) >> 6;
  for (int n = wid; n < N; n += nw) {
    const float hp = h1[n * 64 + lane] + aggr[n * 64 + lane];
    float t = ba_l;
#pragma unroll
    for (int k = 0; k < 64; ++k)
      t = fmaf(__shfl(hp, k, 64), wa[k], t);
    t = fmaxf(t, 0.f);
    float h = bb_l;
#pragma unroll
    for (int k = 0; k < 64; ++k)
      h = fmaf(__shfl(t, k, 64), wb[k], h);
    psum += h;
  }
  __shared__ float red[4][64];
  red[wv][lane] = psum;
  __syncthreads();
  if (threadIdx.x < 64) {
    const float s4 = red[0][lane] + red[1][lane] + red[2][lane] + red[3][lane];
    atomicAdd(&gsum[lane], s4);
  }
}

__global__ __launch_bounds__(256) void k_head(
    const float* __restrict__ gsum,
    const float* __restrict__ Wn1, const float* __restrict__ bn1,
    const float* __restrict__ Wn2, const float* __restrict__ bn2,
    const float* __restrict__ Ws1, const float* __restrict__ bs1,
    const float* __restrict__ Ws2, const float* __restrict__ bs2,
    const float* __restrict__ Wt1, const float* __restrict__ bt1,
    const float* __restrict__ Wt2, const float* __restrict__ bt2,
    float* __restrict__ out, float invN)
{
  __shared__ float g[64], z1[256], z2[128], sa[64], tb[64];
  const int t = threadIdx.x;
  if (t < 64) g[t] = gsum[t] * invN;
  __syncthreads();
  {
    float acc = bn1[t];
    for (int k = 0; k < 64; ++k) acc = fmaf(g[k], Wn1[k * 256 + t], acc);
    z1[t] = fmaxf(acc, 0.f);
  }
  __syncthreads();
  if (t < 128) {
    float acc = bn2[t];
    for (int k = 0; k < 256; ++k) acc = fmaf(z1[k], Wn2[k * 128 + t], acc);
    z2[t] = fmaxf(acc, 0.f);
  }
  __syncthreads();
  if (t < 64) {
    float acc = bs1[t];
    for (int k = 0; k < 128; ++k) acc = fmaf(z2[k], Ws1[k * 64 + t], acc);
    sa[t] = fmaxf(acc, 0.f);
  } else if (t < 128) {
    const int j = t - 64;
    float acc = bt1[j];
    for (int k = 0; k < 128; ++k) acc = fmaf(z2[k], Wt1[k * 64 + j], acc);
    tb[j] = fmaxf(acc, 0.f);
  }
  __syncthreads();
  if (t < 64) {
    float acc = bs2[t];
    for (int k = 0; k < 64; ++k) acc = fmaf(sa[k], Ws2[k * 64 + t], acc);
    out[t] = 1.f / (1.f + __expf(-acc));
  } else if (t < 96) {
    const int j = t - 64;
    float acc = bt2[j];
    for (int k = 0; k < 64; ++k) acc = fmaf(tb[k], Wt2[k * 32 + j], acc);
    out[64 + j] = 1.f / (1.f + __expf(-acc));
  }
}

extern "C" void kernel_launch(void* const* d_in, const int* in_sizes, int n_in,
                              void* d_out, int out_size, void* d_ws, size_t ws_size,
                              hipStream_t stream)
{
  const float* x   = (const float*)d_in[0];
  const float* ea  = (const float*)d_in[1];
  const int*   ei  = (const int*)d_in[2];
  const float* We1 = (const float*)d_in[3];  const float* be1 = (const float*)d_in[4];
  const float* W1a = (const float*)d_in[5];  const float* b1a = (const float*)d_in[6];
  const float* W1b = (const float*)d_in[7];  const float* b1b = (const float*)d_in[8];
  const float* We2 = (const float*)d_in[9];  const float* be2 = (const float*)d_in[10];
  const float* W2a = (const float*)d_in[11]; const float* b2a = (const float*)d_in[12];
  const float* W2b = (const float*)d_in[13]; const float* b2b = (const float*)d_in[14];
  const float* Wn1 = (const float*)d_in[15]; const float* bn1 = (const float*)d_in[16];
  const float* Wn2 = (const float*)d_in[17]; const float* bn2 = (const float*)d_in[18];
  const float* Ws1 = (const float*)d_in[19]; const float* bs1 = (const float*)d_in[20];
  const float* Ws2 = (const float*)d_in[21]; const float* bs2 = (const float*)d_in[22];
  const float* Wt1 = (const float*)d_in[23]; const float* bt1 = (const float*)d_in[24];
  const float* Wt2 = (const float*)d_in[25]; const float* bt2 = (const float*)d_in[26];

  const int N = in_sizes[0] / 32;
  const int E = in_sizes[1] / 16;
  const int* src = ei;
  const int* dst = ei + E;

  char* ws = (char*)d_ws;
  float* h1   = (float*)ws;                              // N*64 f32
  float* aggr = (float*)(ws + (size_t)N * 64 * 4);       // N*64 f32 (layer1 uses N*32)
  float* gsum = (float*)(ws + (size_t)N * 64 * 4 * 2);   // 64 f32, contiguous after aggr

  // Layer 1
  hipMemsetAsync(aggr, 0, (size_t)N * 32 * 4, stream);
  k_edge1<<<2048, 256, 0, stream>>>(x, ea, src, dst, We1, be1, aggr, E);
  k_node1<<<2048, 256, 0, stream>>>(x, aggr, W1a, b1a, W1b, b1b, h1, N);

  // Layer 2 (+ zero gsum in the same memset: contiguous after aggr)
  hipMemsetAsync(aggr, 0, (size_t)N * 64 * 4 + 64 * 4, stream);
  k_edge2<<<2048, 256, 0, stream>>>(h1, ea, src, dst, We2, be2, aggr, E);
  k_node2<<<2048, 256, 0, stream>>>(h1, aggr, W2a, b2a, W2b, b2b, gsum, N);

  // Head
  k_head<<<1, 256, 0, stream>>>(gsum, Wn1, bn1, Wn2, bn2, Ws1, bs1, Ws2, bs2,
                                Wt1, bt1, Wt2, bt2, (float*)d_out, 1.f / (float)N);
}